// Round 6
// baseline (14352.560 us; speedup 1.0000x reference)
//
#include <hip/hip_runtime.h>
#include <hip/hip_cooperative_groups.h>

namespace cg = cooperative_groups;

#define T_SEQ 4096
#define D_IN  512
#define D_H   2048
#define D_C   2560
#define D_OUT 512
#define NBLK  256
#define NTHR  512   // 8 waves, 1 wave per hidden unit, 2 waves/SIMD -> 256 VGPR budget

__device__ __forceinline__ void dot4(float& acc, const float4& a, const float4& b) {
    acc = fmaf(a.x, b.x, acc);
    acc = fmaf(a.y, b.y, acc);
    acc = fmaf(a.z, b.z, acc);
    acc = fmaf(a.w, b.w, acc);
}

__device__ __forceinline__ unsigned long long agload64(const unsigned long long* p) {
    return __hip_atomic_load(p, __ATOMIC_RELAXED, __HIP_MEMORY_SCOPE_AGENT);
}
__device__ __forceinline__ void agstore64(unsigned long long* p, unsigned long long v) {
    __hip_atomic_store(p, v, __ATOMIC_RELAXED, __HIP_MEMORY_SCOPE_AGENT);
}

// Cross-block h exchange: packed (tag<<32 | f32 bits) per unit, double-buffered
// by step parity. Only relaxed agent-scope atomics touch these lines (no
// acquire -> no L2 shootdowns); tag travels WITH data: one L3 trip per hop.
// 2-buffer safety: a producer can publish step t+2 (overwriting slot parity of
// step t) only after observing ALL tags >= t+1, which requires every block to
// have finished staging step t. Single __syncthreads per step: staging for
// t+1 is gated by tags>=t+1 which implies the local waves already published
// (and thus finished reading lds_h for step t).

__global__ __launch_bounds__(NTHR, 2) void lstm_persist(
    const float* __restrict__ x,         // [T_SEQ, D_IN]
    const float* __restrict__ hidden_in, // [D_H] (passthrough output)
    const float* __restrict__ Wi, const float* __restrict__ bi,
    const float* __restrict__ Wg, const float* __restrict__ bg,
    const float* __restrict__ Wo, const float* __restrict__ bo,
    const float* __restrict__ Wout, const float* __restrict__ bout,
    float* __restrict__ out,             // [D_OUT + D_H]
    unsigned long long* __restrict__ hb2)// d_ws: [2][D_H] tagged h
{
    cg::grid_group grid = cg::this_grid();
    const int tid  = threadIdx.x;
    const int lane = tid & 63;
    const int w    = tid >> 6;               // wave 0..7 = unit-local index
    const int j    = blockIdx.x * 8 + w;     // hidden unit 0..2047
    const int kb   = lane * 4;               // lane's 4-elem slice base
    const int s4   = tid * 4;                // this thread's 4 staged units

    __shared__ float lds_h[D_H];

    // ---- init tagged-h buffers (ws poisoned 0xAA every call).
    // slot0 tag0 == h_0 = 0 valid; slot1 tag0 < 1 == not yet written.
    if (blockIdx.x == 0) {
        for (int i = tid; i < 2 * D_H; i += NTHR) agstore64(&hb2[i], 0ull);
    }
    grid.sync();   // one-time: publishes init before anyone polls

    // ---- this wave's FULL rows of Wi/Wg/Wo: 30 float4 = 120 VGPRs, resident
    float4 wiv[10], wgv[10], wov[10];
    {
        const size_t ro = (size_t)j * D_C + kb;
#pragma unroll
        for (int r = 0; r < 10; ++r) {
            wiv[r] = *reinterpret_cast<const float4*>(Wi + ro + 256 * r);
            wgv[r] = *reinterpret_cast<const float4*>(Wg + ro + 256 * r);
            wov[r] = *reinterpret_cast<const float4*>(Wo + ro + 256 * r);
        }
    }
    const float b_i = bi[j];
    const float b_g = bg[j];
    const float b_o = bo[j];

    float4 xv0 = *reinterpret_cast<const float4*>(x + kb);
    float4 xv1 = *reinterpret_cast<const float4*>(x + kb + 256);

#pragma unroll 1
    for (int t = 0; t < T_SEQ; ++t) {
        // ---- x-part of all 3 gate dots: no dependence on h -> before the poll
        float ai = 0.f, ag = 0.f, ao = 0.f;
        dot4(ai, wiv[0], xv0); dot4(ai, wiv[1], xv1);
        dot4(ag, wgv[0], xv0); dot4(ag, wgv[1], xv1);
        dot4(ao, wov[0], xv0); dot4(ao, wov[1], xv1);

        // prefetch next x slice (in flight during the spin)
        const int tn = (t + 1 < T_SEQ) ? t + 1 : t;
        const float4 xn0 = *reinterpret_cast<const float4*>(x + (size_t)tn * D_IN + kb);
        const float4 xn1 = *reinterpret_cast<const float4*>(x + (size_t)tn * D_IN + kb + 256);

        // ---- poll + stage this thread's 4 units (tag check IS the data read)
        const unsigned long long* hb = hb2 + (t & 1) * D_H;
        unsigned long long v0, v1, v2, v3;
        const unsigned tg = (unsigned)t;
        for (;;) {
            v0 = agload64(hb + s4 + 0);
            v1 = agload64(hb + s4 + 1);
            v2 = agload64(hb + s4 + 2);
            v3 = agload64(hb + s4 + 3);
            if ((unsigned)(v0 >> 32) >= tg && (unsigned)(v1 >> 32) >= tg &&
                (unsigned)(v2 >> 32) >= tg && (unsigned)(v3 >> 32) >= tg) break;
            __builtin_amdgcn_s_sleep(1);
        }
        *reinterpret_cast<float4*>(&lds_h[s4]) =
            make_float4(__uint_as_float((unsigned)v0), __uint_as_float((unsigned)v1),
                        __uint_as_float((unsigned)v2), __uint_as_float((unsigned)v3));
        __syncthreads();   // the only barrier per step

        // ---- h-part: rows 2..9 (comb[512..2560)), weights from VGPR
#pragma unroll
        for (int r = 2; r < 10; ++r) {
            const float4 hv = *reinterpret_cast<const float4*>(&lds_h[(r - 2) * 256 + kb]);
            dot4(ai, wiv[r], hv);
            dot4(ag, wgv[r], hv);
            dot4(ao, wov[r], hv);
        }

        // ---- 64-lane butterfly reduce (3 values)
#pragma unroll
        for (int off = 32; off; off >>= 1) {
            ai += __shfl_xor(ai, off, 64);
            ag += __shfl_xor(ag, off, 64);
            ao += __shfl_xor(ao, off, 64);
        }

        // ---- activations (all lanes, redundant), lane 0 publishes tagged h
        const float zi = ai + b_i;
        const float zg = ag + b_g;
        const float zo = ao + b_o;
        const float it = 1.0f / (1.0f + __expf(-zi));
        const float e2g = __expf(-2.0f * zg);
        const float gt = (1.0f - e2g) / (1.0f + e2g);
        const float ot = 1.0f / (1.0f + __expf(-zo));
        const float c  = it * gt;
        const float e2c = __expf(-2.0f * c);
        const float th = (1.0f - e2c) / (1.0f + e2c);
        if (lane == 0) {
            const unsigned long long pk =
                ((unsigned long long)(unsigned)(t + 1) << 32) |
                (unsigned long long)__float_as_uint(ot * th);
            agstore64(&hb2[((t + 1) & 1) * D_H + j], pk);
        }

        xv0 = xn0; xv1 = xn1;
    }

    // ---- epilogue
    if (blockIdx.x < 64) {
        // final h: tag T_SEQ in slot 0 (T_SEQ even)
        unsigned long long v0, v1, v2, v3;
        for (;;) {
            v0 = agload64(hb2 + s4 + 0);
            v1 = agload64(hb2 + s4 + 1);
            v2 = agload64(hb2 + s4 + 2);
            v3 = agload64(hb2 + s4 + 3);
            if ((unsigned)(v0 >> 32) >= (unsigned)T_SEQ &&
                (unsigned)(v1 >> 32) >= (unsigned)T_SEQ &&
                (unsigned)(v2 >> 32) >= (unsigned)T_SEQ &&
                (unsigned)(v3 >> 32) >= (unsigned)T_SEQ) break;
            __builtin_amdgcn_s_sleep(1);
        }
        *reinterpret_cast<float4*>(&lds_h[s4]) =
            make_float4(__uint_as_float((unsigned)v0), __uint_as_float((unsigned)v1),
                        __uint_as_float((unsigned)v2), __uint_as_float((unsigned)v3));
        __syncthreads();

        const int ow = blockIdx.x * 8 + w;   // 8 waves -> rows 0..511
        const float* pw = Wout + (size_t)ow * D_H + kb;
        float acc = 0.f;
#pragma unroll
        for (int r = 0; r < 8; ++r) {
            const float4 w4 = *reinterpret_cast<const float4*>(pw + 256 * r);
            const float4 hv = *reinterpret_cast<const float4*>(&lds_h[kb + 256 * r]);
            dot4(acc, w4, hv);
        }
#pragma unroll
        for (int off = 32; off; off >>= 1) acc += __shfl_xor(acc, off, 64);
        if (lane == 0) out[ow] = acc + bout[ow];
    } else if (blockIdx.x >= 64 && blockIdx.x < 66) {
        // passthrough: out[512 .. 2559] = hidden_in[0 .. 2047]
        const int base = (blockIdx.x - 64) * 1024;
        out[D_OUT + base + tid]       = hidden_in[base + tid];
        out[D_OUT + base + tid + 512] = hidden_in[base + tid + 512];
    }
}

extern "C" void kernel_launch(void* const* d_in, const int* in_sizes, int n_in,
                              void* d_out, int out_size, void* d_ws, size_t ws_size,
                              hipStream_t stream) {
    const float* x      = (const float*)d_in[0];
    const float* hidden = (const float*)d_in[1];
    const float* Wi     = (const float*)d_in[2];
    const float* bi     = (const float*)d_in[3];
    const float* Wg     = (const float*)d_in[4];
    const float* bg     = (const float*)d_in[5];
    const float* Wo     = (const float*)d_in[6];
    const float* bo     = (const float*)d_in[7];
    const float* Wout   = (const float*)d_in[8];
    const float* bout   = (const float*)d_in[9];
    float* out = (float*)d_out;
    unsigned long long* hb2 = (unsigned long long*)d_ws;  // 2*2048*8 = 32 KB

    void* args[] = {(void*)&x, (void*)&hidden, (void*)&Wi, (void*)&bi,
                    (void*)&Wg, (void*)&bg, (void*)&Wo, (void*)&bo,
                    (void*)&Wout, (void*)&bout, (void*)&out, (void*)&hb2};
    (void)hipLaunchCooperativeKernel((const void*)lstm_persist,
                                     dim3(NBLK), dim3(NTHR), args, 0, stream);
}

// Round 7
// 12944.923 us; speedup vs baseline: 1.1087x; 1.1087x over previous
//
#include <hip/hip_runtime.h>
#include <hip/hip_cooperative_groups.h>

namespace cg = cooperative_groups;

#define T_SEQ 4096
#define D_IN  512
#define D_H   2048
#define D_C   2560
#define D_OUT 512
#define NBLK  256
#define NTHR  512
#define UPB   8     // hidden units per block = waves per block

__device__ __forceinline__ void dot4(float& acc, const float4& a, const float4& b) {
    acc = fmaf(a.x, b.x, acc);
    acc = fmaf(a.y, b.y, acc);
    acc = fmaf(a.z, b.z, acc);
    acc = fmaf(a.w, b.w, acc);
}

// ---- DPP wave64 sum: 6 stages, total lands in lane 63. ~5x faster than
// a 6-level ds_swizzle butterfly (VALU pipe, no LDS round trips).
template<int CTRL, int RMASK>
__device__ __forceinline__ float dpp_add(float x) {
    int t = __builtin_amdgcn_update_dpp(0, __float_as_int(x), CTRL, RMASK, 0xf, true);
    return x + __int_as_float(t);
}
__device__ __forceinline__ float wave_red63(float x) {
    x = dpp_add<0x111, 0xf>(x);   // row_shr:1
    x = dpp_add<0x112, 0xf>(x);   // row_shr:2
    x = dpp_add<0x114, 0xf>(x);   // row_shr:4
    x = dpp_add<0x118, 0xf>(x);   // row_shr:8  -> lane 15 of each row16 = row sum
    x = dpp_add<0x142, 0xa>(x);   // row_bcast:15 rows 1,3
    x = dpp_add<0x143, 0xc>(x);   // row_bcast:31 rows 2,3 -> lane 63 = total
    return x;
}

// ---- fast activations (threshold 0.072 >> rcp/exp2 error)
__device__ __forceinline__ float fast_sigmoid(float z) {
    float e = __builtin_amdgcn_exp2f(-1.44269504f * z);
    return __builtin_amdgcn_rcpf(1.0f + e);
}
__device__ __forceinline__ float fast_tanh(float z) {
    float e2 = __builtin_amdgcn_exp2f(2.88539008f * z);   // e^{2z}
    return 1.0f - 2.0f * __builtin_amdgcn_rcpf(e2 + 1.0f);
}

// ---- AGPR pinning (R5-proven): weights live in the accumulator file, the
// allocator cannot rematerialize or cheaply spill them.
#define AW(i, v) asm volatile("v_accvgpr_write_b32 %0, %1" : "=a"(aw[i]) : "v"(v))
#define AR(d, i) asm volatile("v_accvgpr_read_b32 %0, %1" : "=v"(d) : "a"(aw[i]))
#define DOT4A(acc, base, hv) do { float4 _w;                          \
        AR(_w.x, (base) + 0); AR(_w.y, (base) + 1);                   \
        AR(_w.z, (base) + 2); AR(_w.w, (base) + 3);                   \
        dot4(acc, _w, hv); } while (0)

__device__ __forceinline__ unsigned long long agload64(const unsigned long long* p) {
    return __hip_atomic_load(p, __ATOMIC_RELAXED, __HIP_MEMORY_SCOPE_AGENT);
}
__device__ __forceinline__ void agstore64(unsigned long long* p, unsigned long long v) {
    __hip_atomic_store(p, v, __ATOMIC_RELAXED, __HIP_MEMORY_SCOPE_AGENT);
}

// Cross-block h: packed (tag<<32 | f32), double-buffered by parity, relaxed
// agent-scope only (no acquire -> no L2 shootdowns). Tag travels WITH data.

template<int USE_XP>
__global__ __launch_bounds__(NTHR, 2) void lstm_persist(
    const float* __restrict__ x,         // [T_SEQ, D_IN]
    const float* __restrict__ hidden_in, // [D_H] (passthrough output)
    const float* __restrict__ Wi, const float* __restrict__ bi,
    const float* __restrict__ Wg, const float* __restrict__ bg,
    const float* __restrict__ Wo, const float* __restrict__ bo,
    const float* __restrict__ Wout, const float* __restrict__ bout,
    float* __restrict__ out,             // [D_OUT + D_H]
    unsigned long long* __restrict__ hb2)// d_ws: [2][D_H] tagged h (+ XP)
{
    cg::grid_group grid = cg::this_grid();
    const int tid  = threadIdx.x;
    const int lane = tid & 63;
    const int w    = tid >> 6;               // wave 0..7 = unit-local index
    const int j    = blockIdx.x * UPB + w;   // hidden unit 0..2047
    const int kb   = lane * 4;
    const int s4   = tid * 4;                // this thread's 4 staged units

    __shared__ float lds_h[D_H];

    // block-private x-projection region: [T_SEQ][UPB] float4 {zi,zg,zo,_}
    float4* xpb = ((float4*)(hb2 + 2 * D_H)) + (size_t)blockIdx.x * T_SEQ * UPB;

    // ---- init tagged-h buffers (ws poisoned 0xAA every call)
    if (blockIdx.x == 0) {
        for (int i = tid; i < 2 * D_H; i += NTHR) agstore64(&hb2[i], 0ull);
    }

    const float b_i = bi[j];
    const float b_g = bg[j];
    const float b_o = bo[j];

    // ---- prologue: x-projection GEMM (XP mode). Block-private output ->
    // no cross-block coherence needed; biases folded in.
    if (USE_XP) {
        float4 wx0i, wx1i, wx0g, wx1g, wx0o, wx1o;
        const size_t ro = (size_t)j * D_C + kb;
        wx0i = *(const float4*)(Wi + ro); wx1i = *(const float4*)(Wi + ro + 256);
        wx0g = *(const float4*)(Wg + ro); wx1g = *(const float4*)(Wg + ro + 256);
        wx0o = *(const float4*)(Wo + ro); wx1o = *(const float4*)(Wo + ro + 256);
#pragma unroll 2
        for (int t = 0; t < T_SEQ; ++t) {
            const float* xt = x + (size_t)t * D_IN;
            const float4 xv0 = *(const float4*)(xt + kb);
            const float4 xv1 = *(const float4*)(xt + kb + 256);
            float ai = 0.f, ag = 0.f, ao = 0.f;
            dot4(ai, wx0i, xv0); dot4(ai, wx1i, xv1);
            dot4(ag, wx0g, xv0); dot4(ag, wx1g, xv1);
            dot4(ao, wx0o, xv0); dot4(ao, wx1o, xv1);
            ai = wave_red63(ai); ag = wave_red63(ag); ao = wave_red63(ao);
            if (lane == 63)
                xpb[t * UPB + w] = make_float4(ai + b_i, ag + b_g, ao + b_o, 0.f);
        }
    }

    grid.sync();   // one-time: publishes hb2 init (XP is block-private)

    // ---- pin weights in AGPRs.
    // layout: h-part aw[g*32 + r*4 + c], r=0..7  (comb[512..2560))
    //         x-part aw[96 + g*8 + r*4 + c], r=0..1 (fallback only)
    float aw[120];
    {
        const size_t rh = (size_t)j * D_C + 512 + kb;
#pragma unroll
        for (int r = 0; r < 8; ++r) {
            const float4 vi = *(const float4*)(Wi + rh + 256 * r);
            const float4 vg = *(const float4*)(Wg + rh + 256 * r);
            const float4 vo = *(const float4*)(Wo + rh + 256 * r);
            AW(r * 4 + 0, vi.x); AW(r * 4 + 1, vi.y);
            AW(r * 4 + 2, vi.z); AW(r * 4 + 3, vi.w);
            AW(32 + r * 4 + 0, vg.x); AW(32 + r * 4 + 1, vg.y);
            AW(32 + r * 4 + 2, vg.z); AW(32 + r * 4 + 3, vg.w);
            AW(64 + r * 4 + 0, vo.x); AW(64 + r * 4 + 1, vo.y);
            AW(64 + r * 4 + 2, vo.z); AW(64 + r * 4 + 3, vo.w);
        }
        if (!USE_XP) {
            const size_t ro = (size_t)j * D_C + kb;
#pragma unroll
            for (int r = 0; r < 2; ++r) {
                const float4 vi = *(const float4*)(Wi + ro + 256 * r);
                const float4 vg = *(const float4*)(Wg + ro + 256 * r);
                const float4 vo = *(const float4*)(Wo + ro + 256 * r);
                AW(96 + r * 4 + 0, vi.x); AW(96 + r * 4 + 1, vi.y);
                AW(96 + r * 4 + 2, vi.z); AW(96 + r * 4 + 3, vi.w);
                AW(104 + r * 4 + 0, vg.x); AW(104 + r * 4 + 1, vg.y);
                AW(104 + r * 4 + 2, vg.z); AW(104 + r * 4 + 3, vg.w);
                AW(112 + r * 4 + 0, vo.x); AW(112 + r * 4 + 1, vo.y);
                AW(112 + r * 4 + 2, vo.z); AW(112 + r * 4 + 3, vo.w);
            }
        }
    }

    float4 xp = make_float4(0.f, 0.f, 0.f, 0.f);
    float4 xv0 = make_float4(0.f, 0.f, 0.f, 0.f), xv1 = xv0;
    if (USE_XP) {
        xp = xpb[w];                       // t = 0
    } else {
        xv0 = *(const float4*)(x + kb);
        xv1 = *(const float4*)(x + kb + 256);
    }

#pragma unroll 1
    for (int t = 0; t < T_SEQ; ++t) {
        // prefetch t+1 inputs (in flight during the spin)
        const int tn = (t + 1 < T_SEQ) ? t + 1 : t;
        float4 xpn = xp, xn0 = xv0, xn1 = xv1;
        if (USE_XP) {
            xpn = xpb[tn * UPB + w];
        } else {
            xn0 = *(const float4*)(x + (size_t)tn * D_IN + kb);
            xn1 = *(const float4*)(x + (size_t)tn * D_IN + kb + 256);
        }

        // x-part of gate dots (fallback only; XP mode has it precomputed)
        float ai = 0.f, ag = 0.f, ao = 0.f;
        if (!USE_XP) {
            DOT4A(ai, 96, xv0);  DOT4A(ai, 100, xv1);
            DOT4A(ag, 104, xv0); DOT4A(ag, 108, xv1);
            DOT4A(ao, 112, xv0); DOT4A(ao, 116, xv1);
        }

        // ---- poll + stage this thread's 4 units (tag check IS the data read)
        const unsigned long long* hb = hb2 + (t & 1) * D_H;
        unsigned long long v0, v1, v2, v3;
        const unsigned tg = (unsigned)t;
        for (;;) {
            v0 = agload64(hb + s4 + 0);
            v1 = agload64(hb + s4 + 1);
            v2 = agload64(hb + s4 + 2);
            v3 = agload64(hb + s4 + 3);
            if ((unsigned)(v0 >> 32) >= tg && (unsigned)(v1 >> 32) >= tg &&
                (unsigned)(v2 >> 32) >= tg && (unsigned)(v3 >> 32) >= tg) break;
            __builtin_amdgcn_s_sleep(1);
        }
        *reinterpret_cast<float4*>(&lds_h[s4]) =
            make_float4(__uint_as_float((unsigned)v0), __uint_as_float((unsigned)v1),
                        __uint_as_float((unsigned)v2), __uint_as_float((unsigned)v3));
        __syncthreads();

        // ---- h-part: 8 rows x 3 gates, weights from AGPRs
#pragma unroll
        for (int r = 0; r < 8; ++r) {
            const float4 hv = *(const float4*)(&lds_h[r * 256 + kb]);
            DOT4A(ai, r * 4, hv);
            DOT4A(ag, 32 + r * 4, hv);
            DOT4A(ao, 64 + r * 4, hv);
        }

        // ---- DPP reduce -> lane 63
        ai = wave_red63(ai); ag = wave_red63(ag); ao = wave_red63(ao);

        if (lane == 63) {
            float zi, zg, zo;
            if (USE_XP) { zi = ai + xp.x; zg = ag + xp.y; zo = ao + xp.z; }
            else        { zi = ai + b_i;  zg = ag + b_g;  zo = ao + b_o;  }
            const float it = fast_sigmoid(zi);
            const float gt = fast_tanh(zg);
            const float ot = fast_sigmoid(zo);
            const float h  = ot * fast_tanh(it * gt);
            const unsigned long long pk =
                ((unsigned long long)(unsigned)(t + 1) << 32) |
                (unsigned long long)__float_as_uint(h);
            agstore64(&hb2[((t + 1) & 1) * D_H + j], pk);
        }
        __syncthreads();   // close WAR on lds_h before next step's staging

        xp = xpn; xv0 = xn0; xv1 = xn1;
    }

    // ---- epilogue
    if (blockIdx.x < 64) {
        unsigned long long v0, v1, v2, v3;
        for (;;) {
            v0 = agload64(hb2 + s4 + 0);
            v1 = agload64(hb2 + s4 + 1);
            v2 = agload64(hb2 + s4 + 2);
            v3 = agload64(hb2 + s4 + 3);
            if ((unsigned)(v0 >> 32) >= (unsigned)T_SEQ &&
                (unsigned)(v1 >> 32) >= (unsigned)T_SEQ &&
                (unsigned)(v2 >> 32) >= (unsigned)T_SEQ &&
                (unsigned)(v3 >> 32) >= (unsigned)T_SEQ) break;
            __builtin_amdgcn_s_sleep(1);
        }
        *reinterpret_cast<float4*>(&lds_h[s4]) =
            make_float4(__uint_as_float((unsigned)v0), __uint_as_float((unsigned)v1),
                        __uint_as_float((unsigned)v2), __uint_as_float((unsigned)v3));
        __syncthreads();

        const int ow = blockIdx.x * 8 + w;
        const float* pw = Wout + (size_t)ow * D_H + kb;
        float acc = 0.f;
#pragma unroll
        for (int r = 0; r < 8; ++r) {
            const float4 w4 = *(const float4*)(pw + 256 * r);
            const float4 hv = *(const float4*)(&lds_h[kb + 256 * r]);
            dot4(acc, w4, hv);
        }
        acc = wave_red63(acc);
        if (lane == 63) out[ow] = acc + bout[ow];
    } else if (blockIdx.x >= 64 && blockIdx.x < 66) {
        const int base = (blockIdx.x - 64) * 1024;
        out[D_OUT + base + tid]       = hidden_in[base + tid];
        out[D_OUT + base + tid + 512] = hidden_in[base + tid + 512];
    }
}

extern "C" void kernel_launch(void* const* d_in, const int* in_sizes, int n_in,
                              void* d_out, int out_size, void* d_ws, size_t ws_size,
                              hipStream_t stream) {
    const float* x      = (const float*)d_in[0];
    const float* hidden = (const float*)d_in[1];
    const float* Wi     = (const float*)d_in[2];
    const float* bi     = (const float*)d_in[3];
    const float* Wg     = (const float*)d_in[4];
    const float* bg     = (const float*)d_in[5];
    const float* Wo     = (const float*)d_in[6];
    const float* bo     = (const float*)d_in[7];
    const float* Wout   = (const float*)d_in[8];
    const float* bout   = (const float*)d_in[9];
    float* out = (float*)d_out;
    unsigned long long* hb2 = (unsigned long long*)d_ws;

    void* args[] = {(void*)&x, (void*)&hidden, (void*)&Wi, (void*)&bi,
                    (void*)&Wg, (void*)&bg, (void*)&Wo, (void*)&bo,
                    (void*)&Wout, (void*)&bout, (void*)&out, (void*)&hb2};

    const size_t need = (size_t)2 * D_H * sizeof(unsigned long long)
                      + (size_t)T_SEQ * D_H * sizeof(float4);   // 32 KB + 128 MB
    if (ws_size >= need) {
        (void)hipLaunchCooperativeKernel((const void*)lstm_persist<1>,
                                         dim3(NBLK), dim3(NTHR), args, 0, stream);
    } else {
        (void)hipLaunchCooperativeKernel((const void*)lstm_persist<0>,
                                         dim3(NBLK), dim3(NTHR), args, 0, stream);
    }
}

// Round 8
// 9431.927 us; speedup vs baseline: 1.5217x; 1.3725x over previous
//
#include <hip/hip_runtime.h>
#include <hip/hip_fp16.h>
#include <hip/hip_cooperative_groups.h>

namespace cg = cooperative_groups;

#define T_SEQ 4096
#define D_IN  512
#define D_H   2048
#define D_C   2560
#define D_OUT 512
#define NBLK  256
#define NTHR  512
#define UPB   8
#define SPIN_CAP 4096

typedef unsigned int u32;
typedef u32 u32x4 __attribute__((ext_vector_type(4)));

__device__ __forceinline__ void dot4(float& acc, const float4& a, const float4& b) {
    acc = fmaf(a.x, b.x, acc);
    acc = fmaf(a.y, b.y, acc);
    acc = fmaf(a.z, b.z, acc);
    acc = fmaf(a.w, b.w, acc);
}

// DPP wave64 sum -> lane 63
template<int CTRL, int RMASK>
__device__ __forceinline__ float dpp_add(float x) {
    int t = __builtin_amdgcn_update_dpp(0, __float_as_int(x), CTRL, RMASK, 0xf, true);
    return x + __int_as_float(t);
}
__device__ __forceinline__ float wave_red63(float x) {
    x = dpp_add<0x111, 0xf>(x);
    x = dpp_add<0x112, 0xf>(x);
    x = dpp_add<0x114, 0xf>(x);
    x = dpp_add<0x118, 0xf>(x);
    x = dpp_add<0x142, 0xa>(x);
    x = dpp_add<0x143, 0xc>(x);
    return x;
}

__device__ __forceinline__ float fast_sigmoid(float z) {
    float e = __builtin_amdgcn_exp2f(-1.44269504f * z);
    return __builtin_amdgcn_rcpf(1.0f + e);
}
__device__ __forceinline__ float fast_tanh(float z) {
    float e2 = __builtin_amdgcn_exp2f(2.88539008f * z);
    return 1.0f - 2.0f * __builtin_amdgcn_rcpf(e2 + 1.0f);
}

// AGPR pinning (R5-proven): h-weights live in the accumulator file.
#define AW(i, v) asm volatile("v_accvgpr_write_b32 %0, %1" : "=a"(aw[i]) : "v"(v))
#define AR(d, i) asm volatile("v_accvgpr_read_b32 %0, %1" : "=v"(d) : "a"(aw[i]))
#define DOT4A(acc, base, hv) do { float4 _w;                          \
        AR(_w.x, (base) + 0); AR(_w.y, (base) + 1);                   \
        AR(_w.z, (base) + 2); AR(_w.w, (base) + 3);                   \
        dot4(acc, _w, hv); } while (0)

// ---- exchange fabric primitives ----
// L3 (coherence point) load: bypass L1+L2.
__device__ __forceinline__ u32x4 load_quad_l3(const u32* p) {
    u32x4 v;
    asm volatile("global_load_dwordx4 %0, %1, off sc0 sc1\n\ts_waitcnt vmcnt(0)"
                 : "=&v"(v) : "v"(p) : "memory");
    return v;
}
// XCD-local L2 load: bypass L1 only (mirror lines are written ONLY by the
// local relay -> the L2 copy is always the newest; no cross-XCD hazard).
__device__ __forceinline__ u32x4 load_quad_l2(const u32* p) {
    u32x4 v;
    asm volatile("global_load_dwordx4 %0, %1, off sc0\n\ts_waitcnt vmcnt(0)"
                 : "=&v"(v) : "v"(p) : "memory");
    return v;
}
__device__ __forceinline__ void store_quad_l2(u32* p, u32x4 v) {
    asm volatile("global_store_dwordx4 %0, %1, off" :: "v"(p), "v"(v) : "memory");
}
__device__ __forceinline__ bool tags_ok(u32x4 v, u32 tg) {
    return (v.x >> 16) == tg && (v.y >> 16) == tg &&
           (v.z >> 16) == tg && (v.w >> 16) == tg;
}
__device__ __forceinline__ float4 unpackq(u32x4 v) {
    return make_float4(
        __half2float(__ushort_as_half((unsigned short)(v.x & 0xFFFFu))),
        __half2float(__ushort_as_half((unsigned short)(v.y & 0xFFFFu))),
        __half2float(__ushort_as_half((unsigned short)(v.z & 0xFFFFu))),
        __half2float(__ushort_as_half((unsigned short)(v.w & 0xFFFFu))));
}

__global__ __launch_bounds__(NTHR, 2) void lstm_persist(
    const float* __restrict__ x,         // [T_SEQ, D_IN]
    const float* __restrict__ hidden_in, // [D_H] (passthrough output)
    const float* __restrict__ Wi, const float* __restrict__ bi,
    const float* __restrict__ Wg, const float* __restrict__ bg,
    const float* __restrict__ Wo, const float* __restrict__ bo,
    const float* __restrict__ Wout, const float* __restrict__ bout,
    float* __restrict__ out,             // [D_OUT + D_H]
    u32* __restrict__ ws)                // hb2[2][D_H] + mirror[8][2][D_H] + claims[8]
{
    cg::grid_group grid = cg::this_grid();
    const int tid  = threadIdx.x;
    const int lane = tid & 63;
    const int w    = tid >> 6;               // wave 0..7 = unit-local index
    const int j    = blockIdx.x * UPB + w;   // hidden unit 0..2047
    const int kb   = lane * 4;

    u32* hb2    = ws;                        // [2][D_H] packed (tag16|f16)
    u32* mirror = ws + 2 * D_H;              // [8][2][D_H]
    u32* claims = ws + 2 * D_H + 16 * D_H;   // [8]

    __shared__ float lds_h[D_H];
    __shared__ u32 s_relay;

    // ---- init (ws poisoned 0xAA every call). tag0|f16(0) == 0 everywhere:
    // slot0 tag0 == "h_0 = 0 valid"; mirror tag0 valid too.
    if (blockIdx.x == 0) {
        for (int i = tid; i < 2 * D_H + 16 * D_H + 8; i += NTHR)
            __hip_atomic_store(&ws[i], 0u, __ATOMIC_RELAXED, __HIP_MEMORY_SCOPE_AGENT);
    }

    // ---- pin h-part weight rows in AGPRs: 3 gates x 8 float4 = 96 floats.
    // x-part (2 float4/gate) stays in plain VGPRs (small, compiler keeps it).
    float aw[96];
    float4 wxi0, wxi1, wxg0, wxg1, wxo0, wxo1;
    {
        const size_t rh = (size_t)j * D_C + 512 + kb;
#pragma unroll
        for (int r = 0; r < 8; ++r) {
            const float4 vi = *(const float4*)(Wi + rh + 256 * r);
            const float4 vg = *(const float4*)(Wg + rh + 256 * r);
            const float4 vo = *(const float4*)(Wo + rh + 256 * r);
            AW(r * 4 + 0, vi.x); AW(r * 4 + 1, vi.y);
            AW(r * 4 + 2, vi.z); AW(r * 4 + 3, vi.w);
            AW(32 + r * 4 + 0, vg.x); AW(32 + r * 4 + 1, vg.y);
            AW(32 + r * 4 + 2, vg.z); AW(32 + r * 4 + 3, vg.w);
            AW(64 + r * 4 + 0, vo.x); AW(64 + r * 4 + 1, vo.y);
            AW(64 + r * 4 + 2, vo.z); AW(64 + r * 4 + 3, vo.w);
        }
        const size_t ro = (size_t)j * D_C + kb;
        wxi0 = *(const float4*)(Wi + ro); wxi1 = *(const float4*)(Wi + ro + 256);
        wxg0 = *(const float4*)(Wg + ro); wxg1 = *(const float4*)(Wg + ro + 256);
        wxo0 = *(const float4*)(Wo + ro); wxo1 = *(const float4*)(Wo + ro + 256);
    }
    const float b_i = bi[j];
    const float b_g = bg[j];
    const float b_o = bo[j];

    grid.sync();   // one-time: publishes init before anyone polls

    // ---- XCD discovery + relay claim (one relay block per XCD)
    unsigned xcd;
    asm volatile("s_getreg_b32 %0, hwreg(HW_REG_XCC_ID)" : "=s"(xcd));
    xcd &= 7u;
    if (tid == 0) {
        u32 r = __hip_atomic_fetch_add(&claims[xcd], 1u,
                                       __ATOMIC_RELAXED, __HIP_MEMORY_SCOPE_AGENT);
        s_relay = (r == 0u) ? 1u : 0u;
    }
    __syncthreads();
    const bool isRelay = (s_relay != 0u);

    float4 xv0 = *(const float4*)(x + kb);
    float4 xv1 = *(const float4*)(x + kb + 256);

    int use_l2 = 1;   // per-thread fallback latch (insurance, not expected)

#pragma unroll 1
    for (int t = 0; t < T_SEQ; ++t) {
        // ---- x-part of gate dots + next-x prefetch (before the poll)
        float ai = 0.f, ag = 0.f, ao = 0.f;
        dot4(ai, wxi0, xv0); dot4(ai, wxi1, xv1);
        dot4(ag, wxg0, xv0); dot4(ag, wxg1, xv1);
        dot4(ao, wxo0, xv0); dot4(ao, wxo1, xv1);
        const int tn = (t + 1 < T_SEQ) ? t + 1 : t;
        const float4 xn0 = *(const float4*)(x + (size_t)tn * D_IN + kb);
        const float4 xn1 = *(const float4*)(x + (size_t)tn * D_IN + kb + 256);

        // ---- exchange: relay pulls from L3 and fans out via local L2;
        // consumers poll the XCD mirror (L2-latency, zero L3 traffic).
        const u32 tg = (u32)t & 0xFFFFu;
        const u32* gp = hb2 + (t & 1) * D_H + tid * 4;
        u32x4 v;
        if (isRelay) {
            u32* mp = mirror + ((size_t)xcd * 2 + (t & 1)) * D_H + tid * 4;
            for (;;) { v = load_quad_l3(gp); if (tags_ok(v, tg)) break; }
            store_quad_l2(mp, v);
        } else {
            const u32* mp = mirror + ((size_t)xcd * 2 + (t & 1)) * D_H + tid * 4;
            bool got = false;
            if (use_l2) {
                for (int s = 0; s < SPIN_CAP; ++s) {
                    v = load_quad_l2(mp);
                    if (tags_ok(v, tg)) { got = true; break; }
                }
                if (!got) use_l2 = 0;   // mirror path broken -> permanent L3 fallback
            }
            if (!got) {
                for (;;) { v = load_quad_l3(gp); if (tags_ok(v, tg)) break; }
            }
        }
        *(float4*)(&lds_h[tid * 4]) = unpackq(v);
        __syncthreads();   // the only barrier per step

        // ---- h-part: 8 rows x 3 gates, weights from AGPRs
#pragma unroll
        for (int r = 0; r < 8; ++r) {
            const float4 hv = *(const float4*)(&lds_h[r * 256 + kb]);
            DOT4A(ai, r * 4, hv);
            DOT4A(ag, 32 + r * 4, hv);
            DOT4A(ao, 64 + r * 4, hv);
        }

        ai = wave_red63(ai); ag = wave_red63(ag); ao = wave_red63(ao);

        if (lane == 63) {
            const float zi = ai + b_i;
            const float zg = ag + b_g;
            const float zo = ao + b_o;
            const float it = fast_sigmoid(zi);
            const float gt = fast_tanh(zg);
            const float ot = fast_sigmoid(zo);
            const float h  = ot * fast_tanh(it * gt);
            const u32 pk = ((u32)((t + 1) & 0xFFFF) << 16) |
                           (u32)__half_as_ushort(__float2half(h));
            __hip_atomic_store(&hb2[((t + 1) & 1) * D_H + j], pk,
                               __ATOMIC_RELAXED, __HIP_MEMORY_SCOPE_AGENT);
        }
        xv0 = xn0; xv1 = xn1;
    }

    // ---- final relay pass: fan out tag T_SEQ (slot 0, T_SEQ even)
    if (isRelay) {
        const u32 tg = (u32)T_SEQ & 0xFFFFu;
        const u32* gp = hb2 + tid * 4;
        u32* mp = mirror + ((size_t)xcd * 2) * D_H + tid * 4;
        u32x4 v;
        for (;;) { v = load_quad_l3(gp); if (tags_ok(v, tg)) break; }
        store_quad_l2(mp, v);
    }

    // ---- epilogue
    if (blockIdx.x < 64) {
        const u32 tg = (u32)T_SEQ & 0xFFFFu;
        const u32* gp = hb2 + tid * 4;
        const u32* mp = mirror + ((size_t)xcd * 2) * D_H + tid * 4;
        u32x4 v;
        bool got = false;
        if (use_l2) {
            for (int s = 0; s < SPIN_CAP; ++s) {
                v = load_quad_l2(mp);
                if (tags_ok(v, tg)) { got = true; break; }
            }
        }
        if (!got) {
            for (;;) { v = load_quad_l3(gp); if (tags_ok(v, tg)) break; }
        }
        *(float4*)(&lds_h[tid * 4]) = unpackq(v);
        __syncthreads();

        const int ow = blockIdx.x * 8 + w;
        const float* pw = Wout + (size_t)ow * D_H + kb;
        float acc = 0.f;
#pragma unroll
        for (int r = 0; r < 8; ++r) {
            const float4 w4 = *(const float4*)(pw + 256 * r);
            const float4 hv = *(const float4*)(&lds_h[kb + 256 * r]);
            dot4(acc, w4, hv);
        }
        acc = wave_red63(acc);
        if (lane == 63) out[ow] = acc + bout[ow];
    } else if (blockIdx.x >= 64 && blockIdx.x < 66) {
        const int base = (blockIdx.x - 64) * 1024;
        out[D_OUT + base + tid]       = hidden_in[base + tid];
        out[D_OUT + base + tid + 512] = hidden_in[base + tid + 512];
    }
}

extern "C" void kernel_launch(void* const* d_in, const int* in_sizes, int n_in,
                              void* d_out, int out_size, void* d_ws, size_t ws_size,
                              hipStream_t stream) {
    const float* x      = (const float*)d_in[0];
    const float* hidden = (const float*)d_in[1];
    const float* Wi     = (const float*)d_in[2];
    const float* bi     = (const float*)d_in[3];
    const float* Wg     = (const float*)d_in[4];
    const float* bg     = (const float*)d_in[5];
    const float* Wo     = (const float*)d_in[6];
    const float* bo     = (const float*)d_in[7];
    const float* Wout   = (const float*)d_in[8];
    const float* bout   = (const float*)d_in[9];
    float* out = (float*)d_out;
    u32* ws = (u32*)d_ws;   // 16 KB hb2 + 128 KB mirrors + 32 B claims

    void* args[] = {(void*)&x, (void*)&hidden, (void*)&Wi, (void*)&bi,
                    (void*)&Wg, (void*)&bg, (void*)&Wo, (void*)&bo,
                    (void*)&Wout, (void*)&bout, (void*)&out, (void*)&ws};
    (void)hipLaunchCooperativeKernel((const void*)lstm_persist,
                                     dim3(NBLK), dim3(NTHR), args, 0, stream);
}